// Round 3
// baseline (220.592 us; speedup 1.0000x reference)
//
#include <hip/hip_runtime.h>
#include <math.h>

#define D_ 256
#define H_ 8
#define DH_ 32
#define Q_ 36
#define E_ 8
#define WORD_ 20
#define S_ 32928
#define SSUB_ 32768
#define DFF_ 2048
#define NCHUNK 64
#define KC 512

typedef unsigned int u32;
typedef unsigned short u16;
typedef unsigned long long u64;
typedef float f4 __attribute__((ext_vector_type(4)));
typedef short bf8 __attribute__((ext_vector_type(8)));

__device__ __forceinline__ u16 f2bf(float f) {
    u32 u = __float_as_uint(f);
    u32 r = u + 0x7fffu + ((u >> 16) & 1u);
    return (u16)(r >> 16);
}
__device__ __forceinline__ float bf2f(u16 h) { return __uint_as_float(((u32)h) << 16); }

__device__ __forceinline__ f4 mfma16(bf8 a, bf8 b, f4 c) {
    return __builtin_amdgcn_mfma_f32_16x16x32_bf16(a, b, c, 0, 0, 0);
}

// block-wide LN stats over 256 threads
__device__ __forceinline__ void block_ln_stats(float v, float* red, float* red2, int tid,
                                               float& mean, float& var) {
    red[tid] = v; red2[tid] = v * v;
    __syncthreads();
    for (int st = 128; st > 0; st >>= 1) {
        if (tid < st) { red[tid] += red[tid + st]; red2[tid] += red2[tid + st]; }
        __syncthreads();
    }
    mean = red[0] * (1.f / 256.f);
    var = red2[0] * (1.f / 256.f) - mean * mean;
    __syncthreads();
}

// ---------------- K/V projection GEMM (M=32928 pad 33024, N=256, K=256) ----------------
// z==0: K = bf16(mem+pos) @ wk^T + bk  -> Kca layout (H, S, 32) bf16
// z==1: V = bf16(mem)     @ wv^T + bv  -> Vca layout (H*32, S)  bf16 (V^T)
__global__ void __launch_bounds__(256) k_gemm_kv(const float* __restrict__ mem,
                                                 const float* __restrict__ pos,
                                                 const float* __restrict__ w,
                                                 const float* __restrict__ bvec,
                                                 u16* __restrict__ Kca, u16* __restrict__ Vca) {
    __shared__ u16 As[128 * 64];
    __shared__ u16 Bs[128 * 64];
    const int tid = threadIdx.x;
    const int lane = tid & 63, wid = tid >> 6;
    const int wr = wid >> 1, wc = wid & 1;
    const int lr = lane & 15, lg = lane >> 4;
    const int s0 = blockIdx.x * 128, n0 = blockIdx.y * 128;
    const int mode = blockIdx.z;
    const int wbase = 256 * (1 + mode);
    char* Ab = (char*)As; char* Bb = (char*)Bs;

    f4 acc[4][4];
#pragma unroll
    for (int i = 0; i < 4; i++)
#pragma unroll
        for (int j = 0; j < 4; j++) acc[i][j] = (f4){0.f, 0.f, 0.f, 0.f};

    for (int k0 = 0; k0 < 256; k0 += 64) {
#pragma unroll
        for (int i = 0; i < 4; i++) {
            int e = i * 2048 + tid * 8;
            int r = e >> 6, c = e & 63;
            // A tile
            {
                int s = s0 + r;
                float v[8];
                if (s < S_) {
                    const float4* p0 = (const float4*)(mem + (u64)s * 256 + k0 + c);
                    float4 a0 = p0[0], a1 = p0[1];
                    v[0]=a0.x; v[1]=a0.y; v[2]=a0.z; v[3]=a0.w;
                    v[4]=a1.x; v[5]=a1.y; v[6]=a1.z; v[7]=a1.w;
                    if (mode == 0) {
                        const float4* p1 = (const float4*)(pos + (u64)s * 256 + k0 + c);
                        float4 b0 = p1[0], b1_ = p1[1];
                        v[0]+=b0.x; v[1]+=b0.y; v[2]+=b0.z; v[3]+=b0.w;
                        v[4]+=b1_.x; v[5]+=b1_.y; v[6]+=b1_.z; v[7]+=b1_.w;
                    }
                } else {
#pragma unroll
                    for (int j = 0; j < 8; j++) v[j] = 0.f;
                }
                u16 t8[8];
#pragma unroll
                for (int j = 0; j < 8; j++) t8[j] = f2bf(v[j]);
                *(bf8*)(Ab + r * 128 + ((c * 2) ^ ((r & 7) << 4))) = *(bf8*)t8;
            }
            // B tile (weights, row-major (N,K))
            {
                int n = n0 + r;
                const float4* p0 = (const float4*)(w + (u64)(wbase + n) * 256 + k0 + c);
                float4 a0 = p0[0], a1 = p0[1];
                float v[8] = {a0.x,a0.y,a0.z,a0.w,a1.x,a1.y,a1.z,a1.w};
                u16 t8[8];
#pragma unroll
                for (int j = 0; j < 8; j++) t8[j] = f2bf(v[j]);
                *(bf8*)(Bb + r * 128 + ((c * 2) ^ ((r & 7) << 4))) = *(bf8*)t8;
            }
        }
        __syncthreads();
#pragma unroll
        for (int kk = 0; kk < 64; kk += 32) {
            bf8 af[4], bfr[4];
#pragma unroll
            for (int mi = 0; mi < 4; mi++) {
                int row = wr * 64 + mi * 16 + lr;
                af[mi] = *(const bf8*)(Ab + row * 128 + ((kk * 2 + lg * 16) ^ ((row & 7) << 4)));
            }
#pragma unroll
            for (int ni = 0; ni < 4; ni++) {
                int row = wc * 64 + ni * 16 + lr;
                bfr[ni] = *(const bf8*)(Bb + row * 128 + ((kk * 2 + lg * 16) ^ ((row & 7) << 4)));
            }
#pragma unroll
            for (int mi = 0; mi < 4; mi++)
#pragma unroll
                for (int ni = 0; ni < 4; ni++)
                    acc[mi][ni] = mfma16(af[mi], bfr[ni], acc[mi][ni]);
        }
        __syncthreads();
    }
#pragma unroll
    for (int mi = 0; mi < 4; mi++) {
#pragma unroll
        for (int ni = 0; ni < 4; ni++) {
            int n = n0 + wc * 64 + ni * 16 + lr;
            float bias = bvec[wbase + n];
#pragma unroll
            for (int r = 0; r < 4; r++) {
                int s = s0 + wr * 64 + mi * 16 + lg * 4 + r;
                if (s < S_) {
                    float v = acc[mi][ni][r] + bias;
                    if (mode == 0)
                        Kca[((u64)(n >> 5) * S_ + s) * 32 + (n & 31)] = f2bf(v);
                    else
                        Vca[(u64)n * S_ + s] = f2bf(v);
                }
            }
        }
    }
}

// ---------------- SA projections: qkv[(mat*36+row)*256+n] ----------------
__global__ void __launch_bounds__(256) k_saproj(const float* __restrict__ tgt,
                                                const float* __restrict__ qpos,
                                                const float* __restrict__ w,
                                                const float* __restrict__ bvec,
                                                float* __restrict__ qkv) {
    int bx = blockIdx.x;
    int mat = bx / 36, row = bx % 36;
    int n = threadIdx.x;
    __shared__ float xr[256];
    float tv = tgt[row * 256 + n];
    xr[n] = (mat < 2) ? tv + qpos[row * 256 + n] : tv;
    __syncthreads();
    const float* wr_ = w + (u64)(mat * 256 + n) * 256;
    float acc = bvec[mat * 256 + n];
    for (int k = 0; k < 256; k++) acc += xr[k] * wr_[k];
    qkv[(u64)bx * 256 + n] = acc;
}

// ---------------- SA attention per head ----------------
__global__ void __launch_bounds__(256) k_saattn(const float* __restrict__ qkv,
                                                float* __restrict__ osa) {
    int hh = blockIdx.x;
    int tid = threadIdx.x;
    __shared__ float qh[36][32], kh[36][32], vh[36][32];
    __shared__ float sc[36][40];
    for (int i = tid; i < 36 * 32; i += 256) {
        int rr = i >> 5, dd = i & 31;
        qh[rr][dd] = qkv[(u64)(0 + rr) * 256 + hh * 32 + dd];
        kh[rr][dd] = qkv[(u64)(36 + rr) * 256 + hh * 32 + dd];
        vh[rr][dd] = qkv[(u64)(72 + rr) * 256 + hh * 32 + dd];
    }
    __syncthreads();
    for (int i = tid; i < 36 * 36; i += 256) {
        int qi = i / 36, ki = i % 36;
        float s = 0.f;
        for (int k2 = 0; k2 < 32; k2++) s += qh[qi][k2] * kh[ki][k2];
        sc[qi][ki] = s * 0.17677669529663687f;
    }
    __syncthreads();
    if (tid < 36) {
        float mx = sc[tid][0];
        for (int k = 1; k < 36; k++) mx = fmaxf(mx, sc[tid][k]);
        float zz = 0.f;
        for (int k = 0; k < 36; k++) { float p = __expf(sc[tid][k] - mx); sc[tid][k] = p; zz += p; }
        float inv = 1.f / zz;
        for (int k = 0; k < 36; k++) sc[tid][k] *= inv;
    }
    __syncthreads();
    for (int i = tid; i < 36 * 32; i += 256) {
        int qi = i >> 5, dd = i & 31;
        float s = 0.f;
        for (int k2 = 0; k2 < 36; k2++) s += sc[qi][k2] * vh[k2][dd];
        osa[(u64)qi * 256 + hh * 32 + dd] = s;
    }
}

// ---------------- SA out-proj + LN1 + CA q-projection ----------------
__global__ void __launch_bounds__(256) k_ln1(const float* __restrict__ osa,
                                             const float* __restrict__ tgt,
                                             const float* __restrict__ qpos,
                                             const float* __restrict__ swout,
                                             const float* __restrict__ sbout,
                                             const float* __restrict__ g1,
                                             const float* __restrict__ b1ln,
                                             const float* __restrict__ caw,
                                             const float* __restrict__ cab,
                                             float* __restrict__ x1, float* __restrict__ qca) {
    int q = blockIdx.x;
    int n = threadIdx.x;
    __shared__ float orow[256], xq[256], red[256], red2[256];
    orow[n] = osa[(u64)q * 256 + n];
    __syncthreads();
    float acc = sbout[n] + tgt[q * 256 + n];
    const float* wr_ = swout + (u64)n * 256;
    for (int k = 0; k < 256; k++) acc += orow[k] * wr_[k];
    float mean, var;
    block_ln_stats(acc, red, red2, n, mean, var);
    float rstd = rsqrtf(var + 1e-5f);
    float val = (acc - mean) * rstd * g1[n] + b1ln[n];
    x1[(u64)q * 256 + n] = val;
    xq[n] = val + qpos[q * 256 + n];
    __syncthreads();
    float a2 = cab[n];
    const float* wr2 = caw + (u64)n * 256;
    for (int k = 0; k < 256; k++) a2 += xq[k] * wr2[k];
    qca[(u64)q * 256 + n] = a2 * 0.17677669529663687f;
}

// ---------------- flash decode over shared keys: 512 indep waves ----------------
__global__ void __launch_bounds__(256) k_flash(const float* __restrict__ qca,
                                               const u16* __restrict__ Kca,
                                               const u16* __restrict__ Vca,
                                               float* __restrict__ nump,
                                               float* __restrict__ mzp) {
    __shared__ u16 pT[4][48 * 64];
    const int tid = threadIdx.x;
    const int lane = tid & 63, wslot = tid >> 6;
    const int gw = blockIdx.x * 4 + wslot;
    const int h = gw >> 6, chunk = gw & 63;
    const int lr = lane & 15, lg = lane >> 4;
    char* pb = (char*)pT[wslot];

    bf8 qf[3];
#pragma unroll
    for (int nt = 0; nt < 3; nt++) {
        int q = nt * 16 + lr;
        u16 t8[8];
        if (q < Q_) {
            const float* p = qca + (u64)q * 256 + h * 32 + lg * 8;
#pragma unroll
            for (int j = 0; j < 8; j++) t8[j] = f2bf(p[j]);
        } else {
#pragma unroll
            for (int j = 0; j < 8; j++) t8[j] = 0;
        }
        qf[nt] = *(bf8*)t8;
    }
    f4 numT[2][3];
#pragma unroll
    for (int mi = 0; mi < 2; mi++)
#pragma unroll
        for (int nt = 0; nt < 3; nt++) numT[mi][nt] = (f4){0.f, 0.f, 0.f, 0.f};
    float mrun[3] = {-3e38f, -3e38f, -3e38f};
    float zl[3] = {0.f, 0.f, 0.f};
    const int base = chunk * KC;
    const f4 z4 = (f4){0.f, 0.f, 0.f, 0.f};

    for (int b = 0; b < 8; b++) {
        int kb0 = base + b * 64;
        f4 st[4][3];
#pragma unroll
        for (int kt = 0; kt < 4; kt++) {
            bf8 af = *(const bf8*)(Kca + ((u64)h * S_ + kb0 + kt * 16 + lr) * 32 + lg * 8);
#pragma unroll
            for (int nt = 0; nt < 3; nt++) st[kt][nt] = mfma16(af, qf[nt], z4);
        }
#pragma unroll
        for (int nt = 0; nt < 3; nt++) {
            float mx = -3e38f;
#pragma unroll
            for (int kt = 0; kt < 4; kt++)
#pragma unroll
                for (int r = 0; r < 4; r++) mx = fmaxf(mx, st[kt][nt][r]);
            mx = fmaxf(mx, __shfl_xor(mx, 16));
            mx = fmaxf(mx, __shfl_xor(mx, 32));
            float mnew = fmaxf(mrun[nt], mx);
            float al = __expf(mrun[nt] - mnew);
            mrun[nt] = mnew;
            float zs = 0.f;
#pragma unroll
            for (int kt = 0; kt < 4; kt++)
#pragma unroll
                for (int r = 0; r < 4; r++) {
                    float p = __expf(st[kt][nt][r] - mnew);
                    st[kt][nt][r] = p;
                    zs += p;
                }
            zl[nt] = zl[nt] * al + zs;
#pragma unroll
            for (int mi = 0; mi < 2; mi++)
#pragma unroll
                for (int r = 0; r < 4; r++) numT[mi][nt][r] *= al;
            int qrow = nt * 16 + lr;
            int swz = (qrow & 7) << 4;
#pragma unroll
            for (int kt = 0; kt < 4; kt++)
#pragma unroll
                for (int r = 0; r < 4; r += 2) {
                    int keyl = kt * 16 + lg * 4 + r;
                    u32 pk = (u32)f2bf(st[kt][nt][r]) | ((u32)f2bf(st[kt][nt][r + 1]) << 16);
                    *(u32*)(pb + qrow * 128 + ((keyl * 2) ^ swz)) = pk;
                }
        }
#pragma unroll
        for (int kb = 0; kb < 2; kb++) {
            bf8 pf[3];
#pragma unroll
            for (int nt = 0; nt < 3; nt++) {
                int qrow = nt * 16 + lr;
                pf[nt] = *(const bf8*)(pb + qrow * 128 + ((kb * 64 + lg * 16) ^ ((qrow & 7) << 4)));
            }
#pragma unroll
            for (int mi = 0; mi < 2; mi++) {
                bf8 vf = *(const bf8*)(Vca + ((u64)(h * 32 + mi * 16 + lr)) * S_ + kb0 + kb * 32 + lg * 8);
#pragma unroll
                for (int nt = 0; nt < 3; nt++) numT[mi][nt] = mfma16(vf, pf[nt], numT[mi][nt]);
            }
        }
    }
#pragma unroll
    for (int nt = 0; nt < 3; nt++) {
        float z = zl[nt];
        z += __shfl_xor(z, 16);
        z += __shfl_xor(z, 32);
        int q = nt * 16 + lr;
        if (lg == 0 && q < Q_) {
            u64 o = ((u64)(h * 36 + q) * 64 + chunk) * 2;
            mzp[o] = mrun[nt];
            mzp[o + 1] = z;
        }
    }
#pragma unroll
    for (int mi = 0; mi < 2; mi++)
#pragma unroll
        for (int nt = 0; nt < 3; nt++) {
            int q = nt * 16 + lr;
            if (q < Q_) {
#pragma unroll
                for (int r = 0; r < 4; r++)
                    nump[((u64)(h * 36 + q) * 64 + chunk) * 32 + mi * 16 + lg * 4 + r] = numT[mi][nt][r];
            }
        }
}

// ---------------- merge 64 chunk partials per (head,q) ----------------
__global__ void __launch_bounds__(64) k_merge(const float* __restrict__ mzp,
                                              const float* __restrict__ nump,
                                              float* __restrict__ ssum) {
    int idx = blockIdx.x;
    int lane = threadIdx.x;
    float m = mzp[((u64)idx * 64 + lane) * 2];
    float z = mzp[((u64)idx * 64 + lane) * 2 + 1];
    float M = m;
    for (int o = 1; o < 64; o <<= 1) M = fmaxf(M, __shfl_xor(M, o));
    float w = __expf(m - M);
    float Z = z * w;
    for (int o = 1; o < 64; o <<= 1) Z += __shfl_xor(Z, o);
    __shared__ float buf[64][33];
    const float* np = nump + ((u64)idx * 64 + lane) * 32;
    for (int d = 0; d < 32; d++) buf[lane][d] = np[d] * w;
    __syncthreads();
    if (lane < 32) {
        float s = 0.f;
        for (int c = 0; c < 64; c++) s += buf[c][lane];
        ssum[(u64)idx * 34 + 2 + lane] = s;
    }
    if (lane == 0) { ssum[(u64)idx * 34] = M; ssum[(u64)idx * 34 + 1] = Z; }
}

// ---------------- per-expert window + combine + CA out-proj + LN2 ----------------
__global__ void __launch_bounds__(256) k_combine(const float* __restrict__ qca,
                                                 const u16* __restrict__ Kca,
                                                 const u16* __restrict__ Vca,
                                                 const float* __restrict__ ssum,
                                                 const float* __restrict__ x1,
                                                 const float* __restrict__ wout,
                                                 const float* __restrict__ bout,
                                                 const float* __restrict__ g2,
                                                 const float* __restrict__ b2ln,
                                                 float* __restrict__ x2f, u16* __restrict__ x2h) {
    int bx = blockIdx.x;
    int e = bx / 36, q = bx % 36;
    int tid = threadIdx.x;
    __shared__ float pw[8][20], Mh[8], Zh[8], Ssc[8], o[256], red[256], red2[256];
    int h = tid >> 5, d = tid & 31;
    if (d < WORD_) {
        int key = SSUB_ + e * WORD_ + d;
        const float* qp = qca + (u64)q * 256 + h * 32;
        const u16* kp = Kca + ((u64)h * S_ + key) * 32;
        float s = 0.f;
        for (int k = 0; k < 32; k++) s += qp[k] * bf2f(kp[k]);
        pw[h][d] = s;
    }
    __syncthreads();
    if (tid < 8) {
        int hh = tid, ih = hh * 36 + q;
        float Ms = ssum[(u64)ih * 34], Zs = ssum[(u64)ih * 34 + 1];
        float mw = pw[hh][0];
        for (int w = 1; w < WORD_; w++) mw = fmaxf(mw, pw[hh][w]);
        float Me = fmaxf(Ms, mw);
        float Zw = 0.f;
        for (int w = 0; w < WORD_; w++) { float p = __expf(pw[hh][w] - Me); pw[hh][w] = p; Zw += p; }
        float sc = __expf(Ms - Me);
        Mh[hh] = Me; Zh[hh] = Zs * sc + Zw; Ssc[hh] = sc;
    }
    __syncthreads();
    {
        int ih = h * 36 + q;
        float num = ssum[(u64)ih * 34 + 2 + d] * Ssc[h];
        const u16* vp = Vca + ((u64)(h * 32 + d)) * S_ + SSUB_ + e * WORD_;
        for (int w = 0; w < WORD_; w++) num += pw[h][w] * bf2f(vp[w]);
        o[tid] = num / Zh[h];
    }
    __syncthreads();
    int n = tid;
    float acc = bout[n] + x1[(u64)q * 256 + n];
    const float* wr_ = wout + (u64)n * 256;
    for (int k = 0; k < 256; k++) acc += o[k] * wr_[k];
    float mean, var;
    block_ln_stats(acc, red, red2, n, mean, var);
    float rstd = rsqrtf(var + 1e-5f);
    float val = (acc - mean) * rstd * g2[n] + b2ln[n];
    x2f[(u64)bx * 256 + n] = val;
    x2h[(u64)bx * 256 + n] = f2bf(val);
}

// ---------------- FFN1: h = relu(x2 @ w1^T + b1), M=288 pad 384, N=2048, K=256 ----------------
__global__ void __launch_bounds__(256) k_ffn1(const u16* __restrict__ x2h,
                                              const float* __restrict__ w1,
                                              const float* __restrict__ b1v,
                                              u16* __restrict__ hbuf) {
    __shared__ u16 As[128 * 64];
    __shared__ u16 Bs[128 * 64];
    const int tid = threadIdx.x;
    const int lane = tid & 63, wid = tid >> 6;
    const int wr = wid >> 1, wc = wid & 1;
    const int lr = lane & 15, lg = lane >> 4;
    const int s0 = blockIdx.x * 128, n0 = blockIdx.y * 128;
    char* Ab = (char*)As; char* Bb = (char*)Bs;

    f4 acc[4][4];
#pragma unroll
    for (int i = 0; i < 4; i++)
#pragma unroll
        for (int j = 0; j < 4; j++) acc[i][j] = (f4){0.f, 0.f, 0.f, 0.f};

    for (int k0 = 0; k0 < 256; k0 += 64) {
#pragma unroll
        for (int i = 0; i < 4; i++) {
            int e = i * 2048 + tid * 8;
            int r = e >> 6, c = e & 63;
            {
                int s = s0 + r;
                bf8 v;
                if (s < 288) v = *(const bf8*)(x2h + (u64)s * 256 + k0 + c);
                else { u16 t8[8] = {0,0,0,0,0,0,0,0}; v = *(bf8*)t8; }
                *(bf8*)(Ab + r * 128 + ((c * 2) ^ ((r & 7) << 4))) = v;
            }
            {
                int n = n0 + r;
                const float4* p0 = (const float4*)(w1 + (u64)n * 256 + k0 + c);
                float4 a0 = p0[0], a1 = p0[1];
                float v[8] = {a0.x,a0.y,a0.z,a0.w,a1.x,a1.y,a1.z,a1.w};
                u16 t8[8];
#pragma unroll
                for (int j = 0; j < 8; j++) t8[j] = f2bf(v[j]);
                *(bf8*)(Bb + r * 128 + ((c * 2) ^ ((r & 7) << 4))) = *(bf8*)t8;
            }
        }
        __syncthreads();
#pragma unroll
        for (int kk = 0; kk < 64; kk += 32) {
            bf8 af[4], bfr[4];
#pragma unroll
            for (int mi = 0; mi < 4; mi++) {
                int row = wr * 64 + mi * 16 + lr;
                af[mi] = *(const bf8*)(Ab + row * 128 + ((kk * 2 + lg * 16) ^ ((row & 7) << 4)));
            }
#pragma unroll
            for (int ni = 0; ni < 4; ni++) {
                int row = wc * 64 + ni * 16 + lr;
                bfr[ni] = *(const bf8*)(Bb + row * 128 + ((kk * 2 + lg * 16) ^ ((row & 7) << 4)));
            }
#pragma unroll
            for (int mi = 0; mi < 4; mi++)
#pragma unroll
                for (int ni = 0; ni < 4; ni++)
                    acc[mi][ni] = mfma16(af[mi], bfr[ni], acc[mi][ni]);
        }
        __syncthreads();
    }
#pragma unroll
    for (int mi = 0; mi < 4; mi++)
#pragma unroll
        for (int ni = 0; ni < 4; ni++) {
            int n = n0 + wc * 64 + ni * 16 + lr;
            float bias = b1v[n];
#pragma unroll
            for (int r = 0; r < 4; r++) {
                int s = s0 + wr * 64 + mi * 16 + lg * 4 + r;
                if (s < 288) {
                    float v = fmaxf(acc[mi][ni][r] + bias, 0.f);
                    hbuf[(u64)s * 2048 + n] = f2bf(v);
                }
            }
        }
}

// ---------------- FFN2: y = h @ w2^T, K=2048 split in 2 halves ----------------
__global__ void __launch_bounds__(256) k_ffn2(const u16* __restrict__ hbuf,
                                              const float* __restrict__ w2,
                                              float* __restrict__ y0, float* __restrict__ y1) {
    __shared__ u16 As[128 * 64];
    __shared__ u16 Bs[128 * 64];
    const int tid = threadIdx.x;
    const int lane = tid & 63, wid = tid >> 6;
    const int wr = wid >> 1, wc = wid & 1;
    const int lr = lane & 15, lg = lane >> 4;
    const int s0 = blockIdx.x * 128, n0 = blockIdx.y * 128;
    const int z = blockIdx.z;
    char* Ab = (char*)As; char* Bb = (char*)Bs;

    f4 acc[4][4];
#pragma unroll
    for (int i = 0; i < 4; i++)
#pragma unroll
        for (int j = 0; j < 4; j++) acc[i][j] = (f4){0.f, 0.f, 0.f, 0.f};

    for (int k0 = z * 1024; k0 < z * 1024 + 1024; k0 += 64) {
#pragma unroll
        for (int i = 0; i < 4; i++) {
            int e = i * 2048 + tid * 8;
            int r = e >> 6, c = e & 63;
            {
                int s = s0 + r;
                bf8 v;
                if (s < 288) v = *(const bf8*)(hbuf + (u64)s * 2048 + k0 + c);
                else { u16 t8[8] = {0,0,0,0,0,0,0,0}; v = *(bf8*)t8; }
                *(bf8*)(Ab + r * 128 + ((c * 2) ^ ((r & 7) << 4))) = v;
            }
            {
                int n = n0 + r;
                const float4* p0 = (const float4*)(w2 + (u64)n * 2048 + k0 + c);
                float4 a0 = p0[0], a1 = p0[1];
                float v[8] = {a0.x,a0.y,a0.z,a0.w,a1.x,a1.y,a1.z,a1.w};
                u16 t8[8];
#pragma unroll
                for (int j = 0; j < 8; j++) t8[j] = f2bf(v[j]);
                *(bf8*)(Bb + r * 128 + ((c * 2) ^ ((r & 7) << 4))) = *(bf8*)t8;
            }
        }
        __syncthreads();
#pragma unroll
        for (int kk = 0; kk < 64; kk += 32) {
            bf8 af[4], bfr[4];
#pragma unroll
            for (int mi = 0; mi < 4; mi++) {
                int row = wr * 64 + mi * 16 + lr;
                af[mi] = *(const bf8*)(Ab + row * 128 + ((kk * 2 + lg * 16) ^ ((row & 7) << 4)));
            }
#pragma unroll
            for (int ni = 0; ni < 4; ni++) {
                int row = wc * 64 + ni * 16 + lr;
                bfr[ni] = *(const bf8*)(Bb + row * 128 + ((kk * 2 + lg * 16) ^ ((row & 7) << 4)));
            }
#pragma unroll
            for (int mi = 0; mi < 4; mi++)
#pragma unroll
                for (int ni = 0; ni < 4; ni++)
                    acc[mi][ni] = mfma16(af[mi], bfr[ni], acc[mi][ni]);
        }
        __syncthreads();
    }
    float* y = z ? y1 : y0;
#pragma unroll
    for (int mi = 0; mi < 4; mi++)
#pragma unroll
        for (int ni = 0; ni < 4; ni++) {
            int n = n0 + wc * 64 + ni * 16 + lr;
#pragma unroll
            for (int r = 0; r < 4; r++) {
                int s = s0 + wr * 64 + mi * 16 + lg * 4 + r;
                if (s < 288) y[(u64)s * 256 + n] = acc[mi][ni][r];
            }
        }
}

// ---------------- FFN residual + LN3 + output transpose ----------------
__global__ void __launch_bounds__(256) k_ln3(const float* __restrict__ y0,
                                             const float* __restrict__ y1,
                                             const float* __restrict__ b2,
                                             const float* __restrict__ x2f,
                                             const float* __restrict__ g3,
                                             const float* __restrict__ b3,
                                             float* __restrict__ out) {
    int r = blockIdx.x;
    int e = r / 36, q = r % 36;
    int n = threadIdx.x;
    __shared__ float red[256], red2[256];
    float v = x2f[(u64)r * 256 + n] + y0[(u64)r * 256 + n] + y1[(u64)r * 256 + n] + b2[n];
    float mean, var;
    block_ln_stats(v, red, red2, n, mean, var);
    float rstd = rsqrtf(var + 1e-5f);
    float val = (v - mean) * rstd * g3[n] + b3[n];
    out[((u64)q * E_ + e) * 256 + n] = val;
}

extern "C" void kernel_launch(void* const* d_in, const int* in_sizes, int n_in,
                              void* d_out, int out_size, void* d_ws, size_t ws_size,
                              hipStream_t stream) {
    const float* tgt = (const float*)d_in[0];
    const float* mem = (const float*)d_in[1];
    const float* pos = (const float*)d_in[3];
    const float* qpos = (const float*)d_in[4];
    const float* sa_w_in = (const float*)d_in[6];
    const float* sa_b_in = (const float*)d_in[7];
    const float* sa_w_out = (const float*)d_in[8];
    const float* sa_b_out = (const float*)d_in[9];
    const float* ca_w_in = (const float*)d_in[10];
    const float* ca_b_in = (const float*)d_in[11];
    const float* ca_w_out = (const float*)d_in[12];
    const float* ca_b_out = (const float*)d_in[13];
    const float* w1 = (const float*)d_in[14];
    const float* b1 = (const float*)d_in[15];
    const float* w2 = (const float*)d_in[16];
    const float* b2 = (const float*)d_in[17];
    const float* g1 = (const float*)d_in[18];
    const float* bb1 = (const float*)d_in[19];
    const float* g2 = (const float*)d_in[20];
    const float* bb2 = (const float*)d_in[21];
    const float* g3 = (const float*)d_in[22];
    const float* bb3 = (const float*)d_in[23];
    float* out = (float*)d_out;

    char* ws = (char*)d_ws;
    u16* Kca   = (u16*)(ws);                       // 8*32928*32 bf16 = 16,859,136 B
    u16* Vca   = (u16*)(ws + 16859136);            // same
    float* qkv = (float*)(ws + 33718272);          // 3*36*256 f32
    float* osa = (float*)(ws + 33828864);          // 36*256 f32
    float* x1  = (float*)(ws + 33865728);          // 36*256 f32
    float* qca = (float*)(ws + 33902592);          // 36*256 f32
    float* nump= (float*)(ws + 33939456);          // 8*36*64*32 f32
    float* mzp = (float*)(ws + 36298752);          // 8*36*64*2 f32
    float* ssum= (float*)(ws + 36446208);          // 288*34 f32
    float* x2f = (float*)(ws + 36485376);          // 288*256 f32
    u16* x2h   = (u16*)(ws + 36780288);            // 288*256 bf16
    u16* hbuf  = (u16*)(ws + 36927744);            // 288*2048 bf16
    float* y0  = (float*)(ws + 38107392);          // 288*256 f32
    float* y1  = (float*)(ws + 38402304);          // 288*256 f32

    hipLaunchKernelGGL(k_saproj, dim3(108), dim3(256), 0, stream, tgt, qpos, sa_w_in, sa_b_in, qkv);
    hipLaunchKernelGGL(k_saattn, dim3(8), dim3(256), 0, stream, qkv, osa);
    hipLaunchKernelGGL(k_ln1, dim3(36), dim3(256), 0, stream, osa, tgt, qpos, sa_w_out, sa_b_out,
                       g1, bb1, ca_w_in, ca_b_in, x1, qca);
    hipLaunchKernelGGL(k_gemm_kv, dim3(258, 2, 2), dim3(256), 0, stream, mem, pos, ca_w_in, ca_b_in,
                       Kca, Vca);
    hipLaunchKernelGGL(k_flash, dim3(128), dim3(256), 0, stream, qca, Kca, Vca, nump, mzp);
    hipLaunchKernelGGL(k_merge, dim3(288), dim3(64), 0, stream, mzp, nump, ssum);
    hipLaunchKernelGGL(k_combine, dim3(288), dim3(256), 0, stream, qca, Kca, Vca, ssum, x1,
                       ca_w_out, ca_b_out, g2, bb2, x2f, x2h);
    hipLaunchKernelGGL(k_ffn1, dim3(3, 16), dim3(256), 0, stream, x2h, w1, b1, hbuf);
    hipLaunchKernelGGL(k_ffn2, dim3(3, 2, 2), dim3(256), 0, stream, hbuf, w2, y0, y1);
    hipLaunchKernelGGL(k_ln3, dim3(288), dim3(256), 0, stream, y0, y1, b2, x2f, g3, bb3, out);
}